// Round 1
// baseline (565.229 us; speedup 1.0000x reference)
//
#include <hip/hip_runtime.h>
#include <hip/hip_bf16.h>
#include <stdint.h>

// Problem constants
#define B_ 64
#define T_ 512
#define H_ 256
#define D_ 512
#define MS_ 64
#define ML_ 8
#define NST_ 64

typedef unsigned short u16;
typedef __bf16 bf8 __attribute__((ext_vector_type(8)));
typedef float f4 __attribute__((ext_vector_type(4)));

__device__ __forceinline__ u16 f2bf(float f) {
    unsigned u = __builtin_bit_cast(unsigned, f);
    u += 0x7fffu + ((u >> 16) & 1u);   // round-to-nearest-even
    return (u16)(u >> 16);
}
__device__ __forceinline__ float sigm(float x) { return 1.f / (1.f + __expf(-x)); }

// ---------------- prep kernels ----------------

__global__ __launch_bounds__(256) void conv_bf16(const float4* __restrict__ in,
                                                 ushort4* __restrict__ out, int n) {
    int i = blockIdx.x * 256 + threadIdx.x;
    if (i < n) {
        float4 v = in[i];
        ushort4 o;
        o.x = f2bf(v.x); o.y = f2bf(v.y); o.z = f2bf(v.z); o.w = f2bf(v.w);
        out[i] = o;
    }
}

// Wc[dir][gate(1024)][k(768)]: k<512 -> W_ih[gate][k], else W_hh[gate][k-512]
__global__ __launch_bounds__(256) void build_wc(const float* __restrict__ wihf,
                                                const float* __restrict__ whhf,
                                                const float* __restrict__ wihb,
                                                const float* __restrict__ whhb,
                                                u16* __restrict__ wc) {
    int i = blockIdx.x * 256 + threadIdx.x;
    if (i >= 2 * 1024 * 768) return;
    int dir = i / (1024 * 768);
    int rem = i - dir * 1024 * 768;
    int g = rem / 768;
    int k = rem - g * 768;
    const float* wih = dir ? wihb : wihf;
    const float* whh = dir ? whhb : whhf;
    float v = (k < 512) ? wih[g * 512 + k] : whh[g * 256 + (k - 512)];
    wc[i] = f2bf(v);
}

__global__ __launch_bounds__(256) void zero_ws(uint4* __restrict__ dst, int n4) {
    int i = blockIdx.x * 256 + threadIdx.x;
    if (i < n4) { uint4 z = {0u, 0u, 0u, 0u}; dst[i] = z; }
}

// ---------------- span packing ----------------
// One thread per batch row. Spans are strictly sequential (only one open span
// at a time), so a single (sid, cnt) pair suffices.
__global__ __launch_bounds__(64) void pack_spans(const int* __restrict__ bio,
                                                 int* __restrict__ tok,
                                                 int* __restrict__ lenb,
                                                 int* __restrict__ lists,
                                                 int* __restrict__ counts) {
    __shared__ int sc[64];
    int b = threadIdx.x;
    for (int s = 0; s < MS_; ++s) lenb[b * MS_ + s] = 0;
    const int* row = bio + b * T_;
    int sid = -1, cnt = 0;
    for (int t = 0; t < T_; ++t) {
        int v = row[t];
        if (v == 1) {
            ++sid; cnt = 0;
            if (sid < MS_) { tok[(b * MS_ + sid) * ML_ + 0] = t; cnt = 1; lenb[b * MS_ + sid] = 1; }
        } else if (v == 2 && sid >= 0 && sid < MS_) {
            if (cnt < ML_) { tok[(b * MS_ + sid) * ML_ + cnt] = t; ++cnt; lenb[b * MS_ + sid] = cnt; }
        }
    }
    __syncthreads();
    // per-step active lists (deterministic order: by b then s)
    for (int p = 0; p < ML_; ++p) {
        int local = 0;
        for (int s = 0; s < MS_; ++s) local += (lenb[b * MS_ + s] > p) ? 1 : 0;
        sc[b] = local;
        __syncthreads();
        if (b == 0) {
            int acc = 0;
            for (int i = 0; i < 64; ++i) { int v = sc[i]; sc[i] = acc; acc += v; }
            counts[p] = acc;
        }
        __syncthreads();
        int off = sc[b];
        for (int s = 0; s < MS_; ++s)
            if (lenb[b * MS_ + s] > p) lists[p * 4096 + off++] = b * MS_ + s;
        __syncthreads();
    }
}

// ---------------- gate GEMM (per step) ----------------
// Rows: [0, cnt) forward at slots 0.., backward at slots 4096+.
// A row = [ x(token rank) : 512 | h_state : 256 ]  (bf16), B = Wc[dir] (N=1024, K=768)
// Tile 64x64, BK=64, mfma 16x16x32 bf16. LDS stride 72 -> 2-way conflicts only.
__global__ __launch_bounds__(256) void gate_gemm(const u16* __restrict__ xbf,
                                                 const u16* __restrict__ hbf,
                                                 const u16* __restrict__ wc,
                                                 const int* __restrict__ tok,
                                                 const int* __restrict__ lenb,
                                                 const int* __restrict__ lists,
                                                 const int* __restrict__ counts,
                                                 float* __restrict__ gates, int p) {
    int cnt = counts[p];
    int rb = blockIdx.y;            // 0..127 ; 0..63 fwd, 64..127 bwd
    int dir = rb >> 6;
    int base = (rb & 63) * 64;
    if (base >= cnt) return;
    int tid = threadIdx.x;

    __shared__ unsigned xoffs[64], hoffs[64];
    __shared__ u16 As[64 * 72];
    __shared__ u16 Bs[64 * 72];

    if (tid < 64) {
        unsigned xo = 0, ho = 0;
        int idx = base + tid;
        if (idx < cnt) {
            int span = lists[p * 4096 + idx];
            int L = lenb[span];
            int rank = dir ? (L - 1 - p) : p;
            int t = tok[span * ML_ + rank];
            int b = span >> 6;
            xo = (unsigned)(b * T_ + t) * D_;
            ho = (unsigned)(dir * 4096 + span) * H_;
        }
        xoffs[tid] = xo; hoffs[tid] = ho;
    }
    __syncthreads();

    int lane = tid & 63;
    int w16 = (tid >> 6) * 16;      // wave's m-strip
    int mr = lane & 15;
    int q = lane >> 4;
    int q8 = q * 8;
    int n0 = blockIdx.x * 64;
    const u16* wb = wc + (size_t)dir * 1024 * 768;

    f4 acc[4];
    f4 zed = {0.f, 0.f, 0.f, 0.f};
#pragma unroll
    for (int i = 0; i < 4; ++i) acc[i] = zed;

    for (int kt = 0; kt < 12; ++kt) {
        // stage A (64 rows x 64 cols bf16): 512 chunks of 16B, 2 per thread
#pragma unroll
        for (int i = 0; i < 2; ++i) {
            int c = tid + i * 256;
            int row = c >> 3;
            int cc = (c & 7) * 8;
            uint4 v;
            if (kt < 8) v = *(const uint4*)(xbf + xoffs[row] + kt * 64 + cc);
            else        v = *(const uint4*)(hbf + hoffs[row] + (kt - 8) * 64 + cc);
            *(uint4*)&As[row * 72 + cc] = v;
        }
        // stage B (64 gates x 64 k)
#pragma unroll
        for (int i = 0; i < 2; ++i) {
            int c = tid + i * 256;
            int row = c >> 3;
            int cc = (c & 7) * 8;
            uint4 v = *(const uint4*)(wb + (size_t)(n0 + row) * 768 + kt * 64 + cc);
            *(uint4*)&Bs[row * 72 + cc] = v;
        }
        __syncthreads();
#pragma unroll
        for (int kk = 0; kk < 64; kk += 32) {
            bf8 af = *(const bf8*)&As[(w16 + mr) * 72 + kk + q8];
#pragma unroll
            for (int nt = 0; nt < 4; ++nt) {
                bf8 bg = *(const bf8*)&Bs[(nt * 16 + mr) * 72 + kk + q8];
                acc[nt] = __builtin_amdgcn_mfma_f32_16x16x32_bf16(af, bg, acc[nt], 0, 0, 0);
            }
        }
        __syncthreads();
    }

    // epilogue: D[m][n], m = q*4+reg (+w16), n = lane&15 (+nt*16+n0)
#pragma unroll
    for (int nt = 0; nt < 4; ++nt) {
#pragma unroll
        for (int r = 0; r < 4; ++r) {
            int i = w16 + q * 4 + r;
            if (base + i < cnt) {
                int n = n0 + nt * 16 + mr;
                gates[(size_t)(rb * 64 + i) * 1024 + n] = acc[nt][r];
            }
        }
    }
}

// ---------------- pointwise LSTM step ----------------
__global__ __launch_bounds__(256) void lstm_point(const float* __restrict__ gates,
                                                  const int* __restrict__ lists,
                                                  const int* __restrict__ counts,
                                                  const float* __restrict__ b_f,
                                                  const float* __restrict__ b_b,
                                                  float* __restrict__ cbuf,
                                                  u16* __restrict__ hbf,
                                                  float* __restrict__ pooled, int p) {
    int bid = blockIdx.x;           // 0..8191
    int dir = bid >> 12;
    int idx = bid & 4095;
    if (idx >= counts[p]) return;
    int span = lists[p * 4096 + idx];
    int j = threadIdx.x;
    const float* bias = dir ? b_b : b_f;
    const float* g = gates + (size_t)bid * 1024;
    float gi = g[j]       + bias[j];
    float gf = g[256 + j] + bias[256 + j];
    float gg = g[512 + j] + bias[512 + j];
    float go = g[768 + j] + bias[768 + j];
    int si = (dir * 4096 + span) * H_ + j;
    float c = cbuf[si];
    float cn = sigm(gf) * c + sigm(gi) * tanhf(gg);
    float h = sigm(go) * tanhf(cn);
    cbuf[si] = cn;
    hbf[si] = f2bf(h);
    pooled[span * 512 + dir * H_ + j] += h;   // step p < len -> always in mask
}

// ---------------- final scores ----------------
// scores[span][k] = pooled[span][:] . slot_emb[k][:]; len==0 spans have pooled=0.
__global__ __launch_bounds__(256) void scores_k(const float* __restrict__ pooled,
                                                const float* __restrict__ emb,
                                                float* __restrict__ out) {
    __shared__ float ps[16 * 512];
    int g = blockIdx.x;             // 16 spans per block
    int tid = threadIdx.x;
    const float4* src = (const float4*)(pooled + (size_t)g * 16 * 512);
#pragma unroll
    for (int i = 0; i < 8; ++i) ((float4*)ps)[tid + i * 256] = src[tid + i * 256];
    __syncthreads();
    int k = tid & 63;
    int sl = tid >> 6;
    const float4* er = (const float4*)(emb + k * 512);
#pragma unroll
    for (int pass = 0; pass < 4; ++pass) {
        int s = sl + pass * 4;
        const float4* pr = (const float4*)(ps + s * 512);
        float acc = 0.f;
        for (int h4 = 0; h4 < 128; ++h4) {
            float4 e = er[h4];
            float4 v = pr[h4];
            acc += v.x * e.x + v.y * e.y + v.z * e.z + v.w * e.w;
        }
        out[(size_t)(g * 16 + s) * 64 + k] = acc;
    }
}

// ---------------- launch ----------------

extern "C" void kernel_launch(void* const* d_in, const int* in_sizes, int n_in,
                              void* d_out, int out_size, void* d_ws, size_t ws_size,
                              hipStream_t stream) {
    const float* lstm_repr = (const float*)d_in[0];
    const float* W_ih_f = (const float*)d_in[1];
    const float* W_hh_f = (const float*)d_in[2];
    const float* b_f    = (const float*)d_in[3];
    const float* W_ih_b = (const float*)d_in[4];
    const float* W_hh_b = (const float*)d_in[5];
    const float* b_b    = (const float*)d_in[6];
    const float* slot_emb = (const float*)d_in[7];
    const int* bio      = (const int*)d_in[8];
    float* out = (float*)d_out;

    char* ws = (char*)d_ws;
    // layout (bytes):
    u16*  xbf    = (u16*)(ws + 0);              // 64*512*512 bf16      = 33,554,432
    u16*  wc     = (u16*)(ws + 33554432);       // 2*1024*768 bf16      =  3,145,728
    int*  tok    = (int*)(ws + 36700160);       // 4096*8 i32           =    131,072
    int*  lenb   = (int*)(ws + 36831232);       // 4096 i32             =     16,384
    int*  lists  = (int*)(ws + 36847616);       // 8*4096 i32           =    131,072
    int*  counts = (int*)(ws + 36978688);       // 8 i32 (padded 256)
    float* gates = (float*)(ws + 36978944);     // 8192*1024 f32        = 33,554,432
    float* pooled= (float*)(ws + 70533376);     // 4096*512 f32         =  8,388,608  (zeroed)
    float* cbuf  = (float*)(ws + 78921984);     // 2*4096*256 f32       =  8,388,608  (zeroed)
    u16*  hbf    = (u16*)(ws + 87310592);       // 2*4096*256 bf16      =  4,194,304  (zeroed)
    // total: 91,504,896 bytes

    conv_bf16<<<16384, 256, 0, stream>>>((const float4*)lstm_repr, (ushort4*)xbf, 4194304);
    build_wc<<<6144, 256, 0, stream>>>(W_ih_f, W_hh_f, W_ih_b, W_hh_b, wc);
    // zero pooled + cbuf + hbf (contiguous, 20,971,520 B = 1,310,720 uint4)
    zero_ws<<<5120, 256, 0, stream>>>((uint4*)pooled, 1310720);
    pack_spans<<<1, 64, 0, stream>>>(bio, tok, lenb, lists, counts);

    for (int p = 0; p < 8; ++p) {
        gate_gemm<<<dim3(16, 128), 256, 0, stream>>>(xbf, hbf, wc, tok, lenb, lists,
                                                     counts, gates, p);
        lstm_point<<<8192, 256, 0, stream>>>(gates, lists, counts, b_f, b_b,
                                             cbuf, hbf, pooled, p);
    }
    scores_k<<<256, 256, 0, stream>>>(pooled, slot_emb, out);
}

// Round 2
// 366.014 us; speedup vs baseline: 1.5443x; 1.5443x over previous
//
#include <hip/hip_runtime.h>
#include <hip/hip_bf16.h>
#include <stdint.h>

// Problem constants
#define B_ 64
#define T_ 512
#define H_ 256
#define D_ 512
#define MS_ 64
#define ML_ 8
#define NST_ 64

typedef unsigned short u16;
typedef __bf16 bf8 __attribute__((ext_vector_type(8)));
typedef float f4 __attribute__((ext_vector_type(4)));

__device__ __forceinline__ u16 f2bf(float f) {
    unsigned u = __builtin_bit_cast(unsigned, f);
    u += 0x7fffu + ((u >> 16) & 1u);   // round-to-nearest-even
    return (u16)(u >> 16);
}
__device__ __forceinline__ float sigm(float x) { return 1.f / (1.f + __expf(-x)); }

// ---------------- prep kernels ----------------

__global__ __launch_bounds__(256) void conv_bf16(const float4* __restrict__ in,
                                                 ushort4* __restrict__ out, int n) {
    int i = blockIdx.x * 256 + threadIdx.x;
    if (i < n) {
        float4 v = in[i];
        ushort4 o;
        o.x = f2bf(v.x); o.y = f2bf(v.y); o.z = f2bf(v.z); o.w = f2bf(v.w);
        out[i] = o;
    }
}

// Wc[dir][gate(1024)][k(768)]: k<512 -> W_ih[gate][k], else W_hh[gate][k-512]
__global__ __launch_bounds__(256) void build_wc(const float* __restrict__ wihf,
                                                const float* __restrict__ whhf,
                                                const float* __restrict__ wihb,
                                                const float* __restrict__ whhb,
                                                u16* __restrict__ wc) {
    int i = blockIdx.x * 256 + threadIdx.x;
    if (i >= 2 * 1024 * 768) return;
    int dir = i / (1024 * 768);
    int rem = i - dir * 1024 * 768;
    int g = rem / 768;
    int k = rem - g * 768;
    const float* wih = dir ? wihb : wihf;
    const float* whh = dir ? whhb : whhf;
    float v = (k < 512) ? wih[g * 512 + k] : whh[g * 256 + (k - 512)];
    wc[i] = f2bf(v);
}

__global__ __launch_bounds__(256) void zero_ws(uint4* __restrict__ dst, int n4) {
    int i = blockIdx.x * 256 + threadIdx.x;
    if (i < n4) { uint4 z = {0u, 0u, 0u, 0u}; dst[i] = z; }
}

// ---------------- span packing (parallel, 1 block/row, 1 thread/token) -------
// Mirrors the reference's cumsum formulation:
//   sid  = cumsum(bio==1) - 1
//   valid= (B|I) & sid>=0
//   cs   = cumsum(valid); start[sid] = cs at the span's B token
//   rank = cs - start[sid]; ok = valid & sid<64 & rank<8
__global__ __launch_bounds__(512) void pack_spans2(const int* __restrict__ bio,
                                                   int* __restrict__ tok,
                                                   int* __restrict__ lenb) {
    __shared__ int wsum[8];
    __shared__ int start_s[64];
    __shared__ int len_s[64];
    int b = blockIdx.x;
    int t = threadIdx.x;
    int lane = t & 63, w = t >> 6;
    int v = bio[b * T_ + t];
    int bm = (v == 1);
    int im = (v == 2);
    if (t < 64) len_s[t] = 0;

    // scan 1: inclusive cumsum of bm
    int x = bm;
#pragma unroll
    for (int off = 1; off < 64; off <<= 1) {
        int y = __shfl_up(x, off, 64);
        if (lane >= off) x += y;
    }
    if (lane == 63) wsum[w] = x;
    __syncthreads();
    int wof = 0;
    for (int i = 0; i < w; ++i) wof += wsum[i];
    int sid = x + wof - 1;
    int valid = ((bm | im) && sid >= 0) ? 1 : 0;
    __syncthreads();           // wsum reuse

    // scan 2: inclusive cumsum of valid
    x = valid;
#pragma unroll
    for (int off = 1; off < 64; off <<= 1) {
        int y = __shfl_up(x, off, 64);
        if (lane >= off) x += y;
    }
    if (lane == 63) wsum[w] = x;
    __syncthreads();
    wof = 0;
    for (int i = 0; i < w; ++i) wof += wsum[i];
    int cs = x + wof;

    if (bm && sid < MS_) start_s[sid] = cs;   // B token: cs here == start -> rank 0
    __syncthreads();

    if (valid && sid < MS_) {
        int rank = cs - start_s[sid];
        if (rank < ML_) {
            tok[(b * MS_ + sid) * ML_ + rank] = t;
            atomicAdd(&len_s[sid], 1);
        }
    }
    __syncthreads();
    if (t < 64) lenb[b * MS_ + t] = len_s[t];
}

// Per-step compacted active-span lists. One block, 16 spans/thread.
__global__ __launch_bounds__(256) void build_lists(const int* __restrict__ lenb,
                                                   int* __restrict__ lists,
                                                   int* __restrict__ counts) {
    __shared__ int wsum[4];
    int tid = threadIdx.x;
    int lane = tid & 63, w = tid >> 6;
    int len[16];
#pragma unroll
    for (int i = 0; i < 16; ++i) len[i] = lenb[tid * 16 + i];
    for (int p = 0; p < ML_; ++p) {
        int c = 0;
#pragma unroll
        for (int i = 0; i < 16; ++i) c += (len[i] > p) ? 1 : 0;
        int x = c;
#pragma unroll
        for (int off = 1; off < 64; off <<= 1) {
            int y = __shfl_up(x, off, 64);
            if (lane >= off) x += y;
        }
        if (lane == 63) wsum[w] = x;
        __syncthreads();
        int wof = 0;
        for (int i = 0; i < w; ++i) wof += wsum[i];
        int pos = wof + x - c;                 // exclusive prefix
#pragma unroll
        for (int i = 0; i < 16; ++i)
            if (len[i] > p) lists[p * 4096 + pos++] = tid * 16 + i;
        if (tid == 255) counts[p] = pos;       // = grand total
        __syncthreads();
    }
}

// ---------------- gate GEMM (per step) ----------------
// Rows: [0, cnt) forward at slots 0.., backward at slots 4096+.
// A row = [ x(token rank) : 512 | h_state : 256 ]  (bf16), B = Wc[dir] (N=1024, K=768)
// Tile 64x64, BK=64, mfma 16x16x32 bf16. LDS stride 72 -> 2-way conflicts only.
__global__ __launch_bounds__(256) void gate_gemm(const u16* __restrict__ xbf,
                                                 const u16* __restrict__ hbf,
                                                 const u16* __restrict__ wc,
                                                 const int* __restrict__ tok,
                                                 const int* __restrict__ lenb,
                                                 const int* __restrict__ lists,
                                                 const int* __restrict__ counts,
                                                 float* __restrict__ gates, int p) {
    int cnt = counts[p];
    int rb = blockIdx.y;            // 0..127 ; 0..63 fwd, 64..127 bwd
    int dir = rb >> 6;
    int base = (rb & 63) * 64;
    if (base >= cnt) return;
    int tid = threadIdx.x;

    __shared__ unsigned xoffs[64], hoffs[64];
    __shared__ u16 As[64 * 72];
    __shared__ u16 Bs[64 * 72];

    if (tid < 64) {
        unsigned xo = 0, ho = 0;
        int idx = base + tid;
        if (idx < cnt) {
            int span = lists[p * 4096 + idx];
            int L = lenb[span];
            int rank = dir ? (L - 1 - p) : p;
            int t = tok[span * ML_ + rank];
            int b = span >> 6;
            xo = (unsigned)(b * T_ + t) * D_;
            ho = (unsigned)(dir * 4096 + span) * H_;
        }
        xoffs[tid] = xo; hoffs[tid] = ho;
    }
    __syncthreads();

    int lane = tid & 63;
    int w16 = (tid >> 6) * 16;      // wave's m-strip
    int mr = lane & 15;
    int q = lane >> 4;
    int q8 = q * 8;
    int n0 = blockIdx.x * 64;
    const u16* wb = wc + (size_t)dir * 1024 * 768;

    f4 acc[4];
    f4 zed = {0.f, 0.f, 0.f, 0.f};
#pragma unroll
    for (int i = 0; i < 4; ++i) acc[i] = zed;

    for (int kt = 0; kt < 12; ++kt) {
        // stage A (64 rows x 64 cols bf16): 512 chunks of 16B, 2 per thread
#pragma unroll
        for (int i = 0; i < 2; ++i) {
            int c = tid + i * 256;
            int row = c >> 3;
            int cc = (c & 7) * 8;
            uint4 v;
            if (kt < 8) v = *(const uint4*)(xbf + xoffs[row] + kt * 64 + cc);
            else        v = *(const uint4*)(hbf + hoffs[row] + (kt - 8) * 64 + cc);
            *(uint4*)&As[row * 72 + cc] = v;
        }
        // stage B (64 gates x 64 k)
#pragma unroll
        for (int i = 0; i < 2; ++i) {
            int c = tid + i * 256;
            int row = c >> 3;
            int cc = (c & 7) * 8;
            uint4 v = *(const uint4*)(wb + (size_t)(n0 + row) * 768 + kt * 64 + cc);
            *(uint4*)&Bs[row * 72 + cc] = v;
        }
        __syncthreads();
#pragma unroll
        for (int kk = 0; kk < 64; kk += 32) {
            bf8 af = *(const bf8*)&As[(w16 + mr) * 72 + kk + q8];
#pragma unroll
            for (int nt = 0; nt < 4; ++nt) {
                bf8 bg = *(const bf8*)&Bs[(nt * 16 + mr) * 72 + kk + q8];
                acc[nt] = __builtin_amdgcn_mfma_f32_16x16x32_bf16(af, bg, acc[nt], 0, 0, 0);
            }
        }
        __syncthreads();
    }

    // epilogue: D[m][n], m = q*4+reg (+w16), n = lane&15 (+nt*16+n0)
#pragma unroll
    for (int nt = 0; nt < 4; ++nt) {
#pragma unroll
        for (int r = 0; r < 4; ++r) {
            int i = w16 + q * 4 + r;
            if (base + i < cnt) {
                int n = n0 + nt * 16 + mr;
                gates[(size_t)(rb * 64 + i) * 1024 + n] = acc[nt][r];
            }
        }
    }
}

// ---------------- pointwise LSTM step ----------------
__global__ __launch_bounds__(256) void lstm_point(const float* __restrict__ gates,
                                                  const int* __restrict__ lists,
                                                  const int* __restrict__ counts,
                                                  const float* __restrict__ b_f,
                                                  const float* __restrict__ b_b,
                                                  float* __restrict__ cbuf,
                                                  u16* __restrict__ hbf,
                                                  float* __restrict__ pooled, int p) {
    int bid = blockIdx.x;           // 0..8191
    int dir = bid >> 12;
    int idx = bid & 4095;
    if (idx >= counts[p]) return;
    int span = lists[p * 4096 + idx];
    int j = threadIdx.x;
    const float* bias = dir ? b_b : b_f;
    const float* g = gates + (size_t)bid * 1024;
    float gi = g[j]       + bias[j];
    float gf = g[256 + j] + bias[256 + j];
    float gg = g[512 + j] + bias[512 + j];
    float go = g[768 + j] + bias[768 + j];
    int si = (dir * 4096 + span) * H_ + j;
    float c = cbuf[si];
    float cn = sigm(gf) * c + sigm(gi) * tanhf(gg);
    float h = sigm(go) * tanhf(cn);
    cbuf[si] = cn;
    hbf[si] = f2bf(h);
    pooled[span * 512 + dir * H_ + j] += h;   // step p < len -> always in mask
}

// ---------------- final scores ----------------
// scores[span][k] = pooled[span][:] . slot_emb[k][:]; len==0 spans have pooled=0.
__global__ __launch_bounds__(256) void scores_k(const float* __restrict__ pooled,
                                                const float* __restrict__ emb,
                                                float* __restrict__ out) {
    __shared__ float ps[16 * 512];
    int g = blockIdx.x;             // 16 spans per block
    int tid = threadIdx.x;
    const float4* src = (const float4*)(pooled + (size_t)g * 16 * 512);
#pragma unroll
    for (int i = 0; i < 8; ++i) ((float4*)ps)[tid + i * 256] = src[tid + i * 256];
    __syncthreads();
    int k = tid & 63;
    int sl = tid >> 6;
    const float4* er = (const float4*)(emb + k * 512);
#pragma unroll
    for (int pass = 0; pass < 4; ++pass) {
        int s = sl + pass * 4;
        const float4* pr = (const float4*)(ps + s * 512);
        float acc = 0.f;
        for (int h4 = 0; h4 < 128; ++h4) {
            float4 e = er[h4];
            float4 v = pr[h4];
            acc += v.x * e.x + v.y * e.y + v.z * e.z + v.w * e.w;
        }
        out[(size_t)(g * 16 + s) * 64 + k] = acc;
    }
}

// ---------------- launch ----------------

extern "C" void kernel_launch(void* const* d_in, const int* in_sizes, int n_in,
                              void* d_out, int out_size, void* d_ws, size_t ws_size,
                              hipStream_t stream) {
    const float* lstm_repr = (const float*)d_in[0];
    const float* W_ih_f = (const float*)d_in[1];
    const float* W_hh_f = (const float*)d_in[2];
    const float* b_f    = (const float*)d_in[3];
    const float* W_ih_b = (const float*)d_in[4];
    const float* W_hh_b = (const float*)d_in[5];
    const float* b_b    = (const float*)d_in[6];
    const float* slot_emb = (const float*)d_in[7];
    const int* bio      = (const int*)d_in[8];
    float* out = (float*)d_out;

    char* ws = (char*)d_ws;
    // layout (bytes):
    u16*  xbf    = (u16*)(ws + 0);              // 64*512*512 bf16      = 33,554,432
    u16*  wc     = (u16*)(ws + 33554432);       // 2*1024*768 bf16      =  3,145,728
    int*  tok    = (int*)(ws + 36700160);       // 4096*8 i32           =    131,072
    int*  lenb   = (int*)(ws + 36831232);       // 4096 i32             =     16,384
    int*  lists  = (int*)(ws + 36847616);       // 8*4096 i32           =    131,072
    int*  counts = (int*)(ws + 36978688);       // 8 i32 (padded 256)
    float* gates = (float*)(ws + 36978944);     // 8192*1024 f32        = 33,554,432
    float* pooled= (float*)(ws + 70533376);     // 4096*512 f32         =  8,388,608  (zeroed)
    float* cbuf  = (float*)(ws + 78921984);     // 2*4096*256 f32       =  8,388,608  (zeroed)
    u16*  hbf    = (u16*)(ws + 87310592);       // 2*4096*256 bf16      =  4,194,304  (zeroed)
    // total: 91,504,896 bytes

    conv_bf16<<<16384, 256, 0, stream>>>((const float4*)lstm_repr, (ushort4*)xbf, 4194304);
    build_wc<<<6144, 256, 0, stream>>>(W_ih_f, W_hh_f, W_ih_b, W_hh_b, wc);
    // zero pooled + cbuf + hbf (contiguous, 20,971,520 B = 1,310,720 uint4)
    zero_ws<<<5120, 256, 0, stream>>>((uint4*)pooled, 1310720);
    pack_spans2<<<64, 512, 0, stream>>>(bio, tok, lenb);
    build_lists<<<1, 256, 0, stream>>>(lenb, lists, counts);

    for (int p = 0; p < 8; ++p) {
        gate_gemm<<<dim3(16, 128), 256, 0, stream>>>(xbf, hbf, wc, tok, lenb, lists,
                                                     counts, gates, p);
        lstm_point<<<8192, 256, 0, stream>>>(gates, lists, counts, b_f, b_b,
                                             cbuf, hbf, pooled, p);
    }
    scores_k<<<256, 256, 0, stream>>>(pooled, slot_emb, out);
}

// Round 3
// 320.482 us; speedup vs baseline: 1.7637x; 1.1421x over previous
//
#include <hip/hip_runtime.h>
#include <hip/hip_bf16.h>
#include <stdint.h>

// Problem constants
#define B_ 64
#define T_ 512
#define H_ 256
#define D_ 512
#define MS_ 64
#define ML_ 8
#define NST_ 64

typedef unsigned short u16;
typedef __bf16 bf8 __attribute__((ext_vector_type(8)));
typedef float f4 __attribute__((ext_vector_type(4)));

__device__ __forceinline__ u16 f2bf(float f) {
    unsigned u = __builtin_bit_cast(unsigned, f);
    u += 0x7fffu + ((u >> 16) & 1u);   // round-to-nearest-even
    return (u16)(u >> 16);
}
__device__ __forceinline__ float sigm(float x) { return 1.f / (1.f + __expf(-x)); }

// ---------------- prep kernels ----------------

// Wc[dir][gate(1024)][k(768)]: k<512 -> W_ih[gate][k], else W_hh[gate][k-512]
__global__ __launch_bounds__(256) void build_wc(const float* __restrict__ wihf,
                                                const float* __restrict__ whhf,
                                                const float* __restrict__ wihb,
                                                const float* __restrict__ whhb,
                                                u16* __restrict__ wc) {
    int i = blockIdx.x * 256 + threadIdx.x;
    if (i >= 2 * 1024 * 768) return;
    int dir = i / (1024 * 768);
    int rem = i - dir * 1024 * 768;
    int g = rem / 768;
    int k = rem - g * 768;
    const float* wih = dir ? wihb : wihf;
    const float* whh = dir ? whhb : whhf;
    float v = (k < 512) ? wih[g * 512 + k] : whh[g * 256 + (k - 512)];
    wc[i] = f2bf(v);
}

__global__ __launch_bounds__(256) void zero_ws(uint4* __restrict__ dst, int n4) {
    int i = blockIdx.x * 256 + threadIdx.x;
    if (i < n4) { uint4 z = {0u, 0u, 0u, 0u}; dst[i] = z; }
}

// ---------------- span packing (parallel, 1 block/row, 1 thread/token) -------
__global__ __launch_bounds__(512) void pack_spans2(const int* __restrict__ bio,
                                                   int* __restrict__ tok,
                                                   int* __restrict__ lenb) {
    __shared__ int wsum[8];
    __shared__ int start_s[64];
    __shared__ int len_s[64];
    int b = blockIdx.x;
    int t = threadIdx.x;
    int lane = t & 63, w = t >> 6;
    int v = bio[b * T_ + t];
    int bm = (v == 1);
    int im = (v == 2);
    if (t < 64) len_s[t] = 0;

    // scan 1: inclusive cumsum of bm
    int x = bm;
#pragma unroll
    for (int off = 1; off < 64; off <<= 1) {
        int y = __shfl_up(x, off, 64);
        if (lane >= off) x += y;
    }
    if (lane == 63) wsum[w] = x;
    __syncthreads();
    int wof = 0;
    for (int i = 0; i < w; ++i) wof += wsum[i];
    int sid = x + wof - 1;
    int valid = ((bm | im) && sid >= 0) ? 1 : 0;
    __syncthreads();           // wsum reuse

    // scan 2: inclusive cumsum of valid
    x = valid;
#pragma unroll
    for (int off = 1; off < 64; off <<= 1) {
        int y = __shfl_up(x, off, 64);
        if (lane >= off) x += y;
    }
    if (lane == 63) wsum[w] = x;
    __syncthreads();
    wof = 0;
    for (int i = 0; i < w; ++i) wof += wsum[i];
    int cs = x + wof;

    if (bm && sid < MS_) start_s[sid] = cs;   // B token: cs here == start -> rank 0
    __syncthreads();

    if (valid && sid < MS_) {
        int rank = cs - start_s[sid];
        if (rank < ML_) {
            tok[(b * MS_ + sid) * ML_ + rank] = t;
            atomicAdd(&len_s[sid], 1);
        }
    }
    __syncthreads();
    if (t < 64) lenb[b * MS_ + t] = len_s[t];
}

// Per-step compacted active-span lists. One block, 16 spans/thread.
__global__ __launch_bounds__(256) void build_lists(const int* __restrict__ lenb,
                                                   int* __restrict__ lists,
                                                   int* __restrict__ counts) {
    __shared__ int wsum[4];
    int tid = threadIdx.x;
    int lane = tid & 63, w = tid >> 6;
    int len[16];
#pragma unroll
    for (int i = 0; i < 16; ++i) len[i] = lenb[tid * 16 + i];
    for (int p = 0; p < ML_; ++p) {
        int c = 0;
#pragma unroll
        for (int i = 0; i < 16; ++i) c += (len[i] > p) ? 1 : 0;
        int x = c;
#pragma unroll
        for (int off = 1; off < 64; off <<= 1) {
            int y = __shfl_up(x, off, 64);
            if (lane >= off) x += y;
        }
        if (lane == 63) wsum[w] = x;
        __syncthreads();
        int wof = 0;
        for (int i = 0; i < w; ++i) wof += wsum[i];
        int pos = wof + x - c;                 // exclusive prefix
#pragma unroll
        for (int i = 0; i < 16; ++i)
            if (len[i] > p) lists[p * 4096 + pos++] = tid * 16 + i;
        if (tid == 255) counts[p] = pos;       // = grand total
        __syncthreads();
    }
}

// Gather-convert only the tokens spans actually use: xg[span*8+rank][512] bf16.
__global__ __launch_bounds__(64) void conv_gather(const float* __restrict__ repr,
                                                  const int* __restrict__ tok,
                                                  const int* __restrict__ lenb,
                                                  u16* __restrict__ xg) {
    int sr = blockIdx.x;            // span*8 + rank
    int span = sr >> 3, rank = sr & 7;
    if (rank >= lenb[span]) return;
    int t = tok[sr];
    int b = span >> 6;
    const float4* src = (const float4*)(repr + (size_t)(b * T_ + t) * D_);
    ushort4* dst = (ushort4*)(xg + (size_t)sr * D_);
    int i = threadIdx.x;            // 8 elems each
    float4 v0 = src[i * 2], v1 = src[i * 2 + 1];
    ushort4 o0, o1;
    o0.x = f2bf(v0.x); o0.y = f2bf(v0.y); o0.z = f2bf(v0.z); o0.w = f2bf(v0.w);
    o1.x = f2bf(v1.x); o1.y = f2bf(v1.y); o1.z = f2bf(v1.z); o1.w = f2bf(v1.w);
    dst[i * 2] = o0; dst[i * 2 + 1] = o1;
}

// ---------------- gate GEMM (per step) ----------------
// Rows: [0, cnt) forward at slots 0.., backward at slots 4096+.
// A row = [ xg(span,rank) : 512 | h_state : 256 ] (bf16), B = Wc[dir] (N=1024,K=768)
// Tile 64x64, BK=64, mfma 16x16x32 bf16. LDS stride 72 -> 2-way conflicts only.
__global__ __launch_bounds__(256) void gate_gemm(const u16* __restrict__ xg,
                                                 const u16* __restrict__ hbf,
                                                 const u16* __restrict__ wc,
                                                 const int* __restrict__ tok,
                                                 const int* __restrict__ lenb,
                                                 const int* __restrict__ lists,
                                                 const int* __restrict__ counts,
                                                 float* __restrict__ gates, int p) {
    int cnt = counts[p];
    int rb = blockIdx.y;            // 0..127 ; 0..63 fwd, 64..127 bwd
    int dir = rb >> 6;
    int base = (rb & 63) * 64;
    if (base >= cnt) return;
    int tid = threadIdx.x;

    __shared__ unsigned xoffs[64], hoffs[64];
    __shared__ u16 As[64 * 72];
    __shared__ u16 Bs[64 * 72];

    if (tid < 64) {
        unsigned xo = 0, ho = 0;
        int idx = base + tid;
        if (idx < cnt) {
            int span = lists[p * 4096 + idx];
            int L = lenb[span];
            int rank = dir ? (L - 1 - p) : p;
            xo = (unsigned)(span * ML_ + rank) * D_;
            ho = (unsigned)(dir * 4096 + span) * H_;
        }
        xoffs[tid] = xo; hoffs[tid] = ho;
    }
    __syncthreads();

    int lane = tid & 63;
    int w16 = (tid >> 6) * 16;      // wave's m-strip
    int mr = lane & 15;
    int q = lane >> 4;
    int q8 = q * 8;
    int n0 = blockIdx.x * 64;
    const u16* wb = wc + (size_t)dir * 1024 * 768;

    f4 acc[4];
    f4 zed = {0.f, 0.f, 0.f, 0.f};
#pragma unroll
    for (int i = 0; i < 4; ++i) acc[i] = zed;

    for (int kt = 0; kt < 12; ++kt) {
        // stage A (64 rows x 64 cols bf16): 512 chunks of 16B, 2 per thread
#pragma unroll
        for (int i = 0; i < 2; ++i) {
            int c = tid + i * 256;
            int row = c >> 3;
            int cc = (c & 7) * 8;
            uint4 v;
            if (kt < 8) v = *(const uint4*)(xg + xoffs[row] + kt * 64 + cc);
            else        v = *(const uint4*)(hbf + hoffs[row] + (kt - 8) * 64 + cc);
            *(uint4*)&As[row * 72 + cc] = v;
        }
        // stage B (64 gates x 64 k)
#pragma unroll
        for (int i = 0; i < 2; ++i) {
            int c = tid + i * 256;
            int row = c >> 3;
            int cc = (c & 7) * 8;
            uint4 v = *(const uint4*)(wb + (size_t)(n0 + row) * 768 + kt * 64 + cc);
            *(uint4*)&Bs[row * 72 + cc] = v;
        }
        __syncthreads();
#pragma unroll
        for (int kk = 0; kk < 64; kk += 32) {
            bf8 af = *(const bf8*)&As[(w16 + mr) * 72 + kk + q8];
#pragma unroll
            for (int nt = 0; nt < 4; ++nt) {
                bf8 bg = *(const bf8*)&Bs[(nt * 16 + mr) * 72 + kk + q8];
                acc[nt] = __builtin_amdgcn_mfma_f32_16x16x32_bf16(af, bg, acc[nt], 0, 0, 0);
            }
        }
        __syncthreads();
    }

    // epilogue: D[m][n], m = q*4+reg (+w16), n = lane&15 (+nt*16+n0)
#pragma unroll
    for (int nt = 0; nt < 4; ++nt) {
#pragma unroll
        for (int r = 0; r < 4; ++r) {
            int i = w16 + q * 4 + r;
            if (base + i < cnt) {
                int n = n0 + nt * 16 + mr;
                gates[(size_t)(rb * 64 + i) * 1024 + n] = acc[nt][r];
            }
        }
    }
}

// ---------------- pointwise LSTM step ----------------
__global__ __launch_bounds__(256) void lstm_point(const float* __restrict__ gates,
                                                  const int* __restrict__ lists,
                                                  const int* __restrict__ counts,
                                                  const float* __restrict__ b_f,
                                                  const float* __restrict__ b_b,
                                                  float* __restrict__ cbuf,
                                                  u16* __restrict__ hbf,
                                                  float* __restrict__ pooled, int p) {
    int bid = blockIdx.x;           // 0..8191
    int dir = bid >> 12;
    int idx = bid & 4095;
    if (idx >= counts[p]) return;
    int span = lists[p * 4096 + idx];
    int j = threadIdx.x;
    const float* bias = dir ? b_b : b_f;
    const float* g = gates + (size_t)bid * 1024;
    float gi = g[j]       + bias[j];
    float gf = g[256 + j] + bias[256 + j];
    float gg = g[512 + j] + bias[512 + j];
    float go = g[768 + j] + bias[768 + j];
    int si = (dir * 4096 + span) * H_ + j;
    float c = cbuf[si];
    float cn = sigm(gf) * c + sigm(gi) * tanhf(gg);
    float h = sigm(go) * tanhf(cn);
    cbuf[si] = cn;
    hbf[si] = f2bf(h);
    pooled[span * 512 + dir * H_ + j] += h;   // step p < len -> always in mask
}

// ---------------- final scores: MFMA GEMM [4096x512] x [512x64] ----------------
// A = pooled (f32 -> bf16 on stage), B = slot_emb (f32 -> bf16 on stage).
// One block per 64-row strip; all N=64 in-block. len==0 spans have pooled=0.
__global__ __launch_bounds__(256) void scores_mfma(const float* __restrict__ pooled,
                                                   const float* __restrict__ emb,
                                                   float* __restrict__ out) {
    int g = blockIdx.x;             // 64 blocks x 64 rows
    int tid = threadIdx.x;

    __shared__ u16 As[64 * 72];
    __shared__ u16 Bs[64 * 72];

    int lane = tid & 63;
    int w16 = (tid >> 6) * 16;
    int mr = lane & 15;
    int q = lane >> 4;
    int q8 = q * 8;

    f4 acc[4];
    f4 zed = {0.f, 0.f, 0.f, 0.f};
#pragma unroll
    for (int i = 0; i < 4; ++i) acc[i] = zed;

    for (int kt = 0; kt < 8; ++kt) {
#pragma unroll
        for (int i = 0; i < 2; ++i) {
            int c = tid + i * 256;
            int row = c >> 3;
            int cc = (c & 7) * 8;
            const float4* a = (const float4*)(pooled + (size_t)(g * 64 + row) * 512 + kt * 64 + cc);
            float4 v0 = a[0], v1 = a[1];
            ushort4 o0, o1;
            o0.x = f2bf(v0.x); o0.y = f2bf(v0.y); o0.z = f2bf(v0.z); o0.w = f2bf(v0.w);
            o1.x = f2bf(v1.x); o1.y = f2bf(v1.y); o1.z = f2bf(v1.z); o1.w = f2bf(v1.w);
            *(ushort4*)&As[row * 72 + cc] = o0;
            *(ushort4*)&As[row * 72 + cc + 4] = o1;
            const float4* b = (const float4*)(emb + (size_t)row * 512 + kt * 64 + cc);
            float4 w0 = b[0], w1 = b[1];
            ushort4 p0, p1;
            p0.x = f2bf(w0.x); p0.y = f2bf(w0.y); p0.z = f2bf(w0.z); p0.w = f2bf(w0.w);
            p1.x = f2bf(w1.x); p1.y = f2bf(w1.y); p1.z = f2bf(w1.z); p1.w = f2bf(w1.w);
            *(ushort4*)&Bs[row * 72 + cc] = p0;
            *(ushort4*)&Bs[row * 72 + cc + 4] = p1;
        }
        __syncthreads();
#pragma unroll
        for (int kk = 0; kk < 64; kk += 32) {
            bf8 af = *(const bf8*)&As[(w16 + mr) * 72 + kk + q8];
#pragma unroll
            for (int nt = 0; nt < 4; ++nt) {
                bf8 bg = *(const bf8*)&Bs[(nt * 16 + mr) * 72 + kk + q8];
                acc[nt] = __builtin_amdgcn_mfma_f32_16x16x32_bf16(af, bg, acc[nt], 0, 0, 0);
            }
        }
        __syncthreads();
    }

#pragma unroll
    for (int nt = 0; nt < 4; ++nt) {
#pragma unroll
        for (int r = 0; r < 4; ++r) {
            int m = g * 64 + w16 + q * 4 + r;
            int n = nt * 16 + mr;
            out[(size_t)m * 64 + n] = acc[nt][r];
        }
    }
}

// ---------------- launch ----------------

extern "C" void kernel_launch(void* const* d_in, const int* in_sizes, int n_in,
                              void* d_out, int out_size, void* d_ws, size_t ws_size,
                              hipStream_t stream) {
    const float* lstm_repr = (const float*)d_in[0];
    const float* W_ih_f = (const float*)d_in[1];
    const float* W_hh_f = (const float*)d_in[2];
    const float* b_f    = (const float*)d_in[3];
    const float* W_ih_b = (const float*)d_in[4];
    const float* W_hh_b = (const float*)d_in[5];
    const float* b_b    = (const float*)d_in[6];
    const float* slot_emb = (const float*)d_in[7];
    const int* bio      = (const int*)d_in[8];
    float* out = (float*)d_out;

    char* ws = (char*)d_ws;
    // layout (bytes):
    u16*  xg     = (u16*)(ws + 0);              // 4096*8*512 bf16      = 33,554,432
    u16*  wc     = (u16*)(ws + 33554432);       // 2*1024*768 bf16      =  3,145,728
    int*  tok    = (int*)(ws + 36700160);       // 4096*8 i32           =    131,072
    int*  lenb   = (int*)(ws + 36831232);       // 4096 i32             =     16,384
    int*  lists  = (int*)(ws + 36847616);       // 8*4096 i32           =    131,072
    int*  counts = (int*)(ws + 36978688);       // 8 i32 (padded 256)
    float* gates = (float*)(ws + 36978944);     // 8192*1024 f32        = 33,554,432
    float* pooled= (float*)(ws + 70533376);     // 4096*512 f32         =  8,388,608  (zeroed)
    float* cbuf  = (float*)(ws + 78921984);     // 2*4096*256 f32       =  8,388,608  (zeroed)
    u16*  hbf    = (u16*)(ws + 87310592);       // 2*4096*256 bf16      =  4,194,304  (zeroed)
    // total: 91,504,896 bytes

    build_wc<<<6144, 256, 0, stream>>>(W_ih_f, W_hh_f, W_ih_b, W_hh_b, wc);
    // zero pooled + cbuf + hbf (contiguous, 20,971,520 B = 1,310,720 uint4)
    zero_ws<<<5120, 256, 0, stream>>>((uint4*)pooled, 1310720);
    pack_spans2<<<64, 512, 0, stream>>>(bio, tok, lenb);
    build_lists<<<1, 256, 0, stream>>>(lenb, lists, counts);
    conv_gather<<<32768, 64, 0, stream>>>(lstm_repr, tok, lenb, xg);

    for (int p = 0; p < 8; ++p) {
        gate_gemm<<<dim3(16, 128), 256, 0, stream>>>(xg, hbf, wc, tok, lenb, lists,
                                                     counts, gates, p);
        lstm_point<<<8192, 256, 0, stream>>>(gates, lists, counts, b_f, b_b,
                                             cbuf, hbf, pooled, p);
    }
    scores_mfma<<<64, 256, 0, stream>>>(pooled, slot_emb, out);
}